// Round 1
// baseline (1675.774 us; speedup 1.0000x reference)
//
#include <hip/hip_runtime.h>
#include <math.h>

#define NSEG 440
#define CF   2112
#define HW   65536
#define NH   1024

// ---------------- ws layout (floats) ----------------
// hist : 0        (440*3 = 1320)
// feat : 2048     (440*2112 = 929280)
// h1   : 931328   (440*1024 = 450560)
// h2   : 1381888  (440*1024 = 450560)
// aff  : 1832448  (440*440  = 193600)
// invn : 2026048  (440)
// lab  : 2026488  (440 ints)
#define OFF_HIST 0
#define OFF_FEAT 2048
#define OFF_H1   931328
#define OFF_H2   1381888
#define OFF_AFF  1832448
#define OFF_INVN 2026048
#define OFF_LAB  2026488

// ---------------- histogram of y per segment (also gives counts) -------------
__global__ __launch_bounds__(256) void hist_kernel(const int* __restrict__ sp,
                                                   const int* __restrict__ y,
                                                   float* __restrict__ hist) {
    __shared__ float lh[NSEG * 3];
    int t = threadIdx.x;
    for (int i = t; i < NSEG * 3; i += 256) lh[i] = 0.0f;
    __syncthreads();
    int idx = blockIdx.x * 256 + t;
    for (int p = idx; p < HW; p += 64 * 256) {
        int s  = sp[p];
        int yy = y[p];
        atomicAdd(&lh[s * 3 + yy], 1.0f);
    }
    __syncthreads();
    for (int i = t; i < NSEG * 3; i += 256)
        if (lh[i] != 0.0f) atomicAdd(&hist[i], lh[i]);
}

// ---------------- per-channel segment sum -> feat (divided by count) ---------
__global__ __launch_bounds__(256) void segsum_kernel(const float* __restrict__ fm,
                                                     const int* __restrict__ sp,
                                                     const float* __restrict__ hist,
                                                     float* __restrict__ feat) {
    __shared__ float seg[NSEG];
    int t = threadIdx.x;
    int c = blockIdx.x;
    for (int s = t; s < NSEG; s += 256) seg[s] = 0.0f;
    __syncthreads();
    const float* f = fm + (size_t)c * HW;
    for (int it = 0; it < 64; ++it) {
        int p = it * 1024 + t * 4;
        float4 v = *(const float4*)(f + p);
        int4  si = *(const int4*)(sp + p);
        atomicAdd(&seg[si.x], v.x);
        atomicAdd(&seg[si.y], v.y);
        atomicAdd(&seg[si.z], v.z);
        atomicAdd(&seg[si.w], v.w);
    }
    __syncthreads();
    for (int s = t; s < NSEG; s += 256) {
        float cnt = hist[3 * s] + hist[3 * s + 1] + hist[3 * s + 2];
        feat[(size_t)s * CF + c] = seg[s] / fmaxf(cnt, 1.0f);
    }
}

// ---------------- labels from histogram (argmax, first-max ties) -------------
__global__ void lab_kernel(const float* __restrict__ hist, int* __restrict__ lab) {
    int s = blockIdx.x * 256 + threadIdx.x;
    if (s >= NSEG) return;
    float h0 = hist[3 * s], h1 = hist[3 * s + 1], h2 = hist[3 * s + 2];
    int l = 0; float b = h0;
    if (h1 > b) { l = 1; b = h1; }
    if (h2 > b) { l = 2; b = h2; }
    if (l == 0) l = (h2 > h1) ? 2 : ((h1 > h2) ? 1 : 0);
    lab[s] = l;
}

// ---------------- fp32 GEMM  C = relu(A(MxK) @ B(KxN) + bias) ----------------
// 64x64 tile, BK=16, 256 threads, 4x4 per thread. K,N multiples of 16/64.
template <int RELU>
__global__ __launch_bounds__(256) void gemm_nn(const float* __restrict__ A,
                                               const float* __restrict__ B,
                                               const float* __restrict__ bias,
                                               float* __restrict__ C,
                                               int M, int N, int K) {
    __shared__ __align__(16) float As[16][64];
    __shared__ __align__(16) float Bs[16][64];
    int t  = threadIdx.x;
    int n0 = blockIdx.x * 64;
    int m0 = blockIdx.y * 64;
    int ty = t >> 4, tx = t & 15;
    int arow = t >> 2, acol = (t & 3) * 4;
    int brow = t >> 4, bcol = (t & 15) * 4;
    float acc[4][4] = {};
    for (int k0 = 0; k0 < K; k0 += 16) {
        float4 av;
        int m = m0 + arow;
        if (m < M) av = *(const float4*)(A + (size_t)m * K + k0 + acol);
        else       av = make_float4(0.f, 0.f, 0.f, 0.f);
        As[acol + 0][arow] = av.x;
        As[acol + 1][arow] = av.y;
        As[acol + 2][arow] = av.z;
        As[acol + 3][arow] = av.w;
        float4 bv = *(const float4*)(B + (size_t)(k0 + brow) * N + n0 + bcol);
        *(float4*)&Bs[brow][bcol] = bv;
        __syncthreads();
#pragma unroll
        for (int kk = 0; kk < 16; ++kk) {
            float4 a = *(const float4*)&As[kk][ty * 4];
            float4 b = *(const float4*)&Bs[kk][tx * 4];
            float ar[4] = {a.x, a.y, a.z, a.w};
            float br[4] = {b.x, b.y, b.z, b.w};
#pragma unroll
            for (int i = 0; i < 4; ++i)
#pragma unroll
                for (int j = 0; j < 4; ++j) acc[i][j] += ar[i] * br[j];
        }
        __syncthreads();
    }
#pragma unroll
    for (int i = 0; i < 4; ++i) {
        int m = m0 + ty * 4 + i;
        if (m < M) {
#pragma unroll
            for (int j = 0; j < 4; ++j) {
                int n = n0 + tx * 4 + j;
                float v = acc[i][j] + bias[n];
                if (RELU) v = fmaxf(v, 0.0f);
                C[(size_t)m * N + n] = v;
            }
        }
    }
}

// ---------------- row inverse norms of feat ----------------------------------
__global__ __launch_bounds__(256) void norm_kernel(const float* __restrict__ feat,
                                                   float* __restrict__ invn) {
    int s = blockIdx.x;
    int t = threadIdx.x;
    const float* r = feat + (size_t)s * CF;
    float acc = 0.0f;
    for (int c = t * 4; c < CF; c += 1024) {
        float4 v = *(const float4*)(r + c);
        acc += v.x * v.x + v.y * v.y + v.z * v.z + v.w * v.w;
    }
    for (int off = 32; off; off >>= 1) acc += __shfl_down(acc, off);
    __shared__ float w[4];
    if ((t & 63) == 0) w[t >> 6] = acc;
    __syncthreads();
    if (t == 0) {
        float tot = w[0] + w[1] + w[2] + w[3];
        invn[s] = 1.0f / sqrtf(fmaxf(tot, 1e-30f));
    }
}

// ---------------- affinity: aff = exp(-(feat@featT) * invn_i * invn_j) -------
__global__ __launch_bounds__(256) void gemm_nt_aff(const float* __restrict__ feat,
                                                   const float* __restrict__ invn,
                                                   float* __restrict__ aff) {
    __shared__ __align__(16) float As[16][64];
    __shared__ __align__(16) float Bs[16][64];
    int t  = threadIdx.x;
    int n0 = blockIdx.x * 64;
    int m0 = blockIdx.y * 64;
    int ty = t >> 4, tx = t & 15;
    int arow = t >> 2, acol = (t & 3) * 4;
    float acc[4][4] = {};
    for (int k0 = 0; k0 < CF; k0 += 16) {
        float4 av, bv;
        int m = m0 + arow;
        if (m < NSEG) av = *(const float4*)(feat + (size_t)m * CF + k0 + acol);
        else          av = make_float4(0.f, 0.f, 0.f, 0.f);
        int n = n0 + arow;
        if (n < NSEG) bv = *(const float4*)(feat + (size_t)n * CF + k0 + acol);
        else          bv = make_float4(0.f, 0.f, 0.f, 0.f);
        As[acol + 0][arow] = av.x;
        As[acol + 1][arow] = av.y;
        As[acol + 2][arow] = av.z;
        As[acol + 3][arow] = av.w;
        Bs[acol + 0][arow] = bv.x;
        Bs[acol + 1][arow] = bv.y;
        Bs[acol + 2][arow] = bv.z;
        Bs[acol + 3][arow] = bv.w;
        __syncthreads();
#pragma unroll
        for (int kk = 0; kk < 16; ++kk) {
            float4 a = *(const float4*)&As[kk][ty * 4];
            float4 b = *(const float4*)&Bs[kk][tx * 4];
            float ar[4] = {a.x, a.y, a.z, a.w};
            float br[4] = {b.x, b.y, b.z, b.w};
#pragma unroll
            for (int i = 0; i < 4; ++i)
#pragma unroll
                for (int j = 0; j < 4; ++j) acc[i][j] += ar[i] * br[j];
        }
        __syncthreads();
    }
#pragma unroll
    for (int i = 0; i < 4; ++i) {
        int m = m0 + ty * 4 + i;
        if (m < NSEG) {
            float im = invn[m];
#pragma unroll
            for (int j = 0; j < 4; ++j) {
                int n = n0 + tx * 4 + j;
                if (n < NSEG)
                    aff[(size_t)m * NSEG + n] = expf(-acc[i][j] * im * invn[n]);
            }
        }
    }
}

// ---------------- fused layer3 + classifier + softmax ------------------------
__global__ __launch_bounds__(256) void head_kernel(const float* __restrict__ h2,
                                                   const float* __restrict__ W3,
                                                   const float* __restrict__ b3,
                                                   const float* __restrict__ Wc,
                                                   const float* __restrict__ bc,
                                                   float* __restrict__ out) {
    int s = blockIdx.x;
    int t = threadIdx.x;
    int d = t & 31, p = t >> 5;   // 8 k-chunks of 128
    const float* row = h2 + (size_t)s * NH;
    float acc = 0.0f;
    int kend = p * 128 + 128;
    for (int k = p * 128; k < kend; ++k) acc += row[k] * W3[k * 32 + d];
    __shared__ float red[8][32];
    __shared__ float h3[32];
    red[p][d] = acc;
    __syncthreads();
    if (t < 32) {
        float v = 0.0f;
#pragma unroll
        for (int q = 0; q < 8; ++q) v += red[q][t];
        v += b3[t];
        h3[t] = fmaxf(v, 0.0f);
    }
    __syncthreads();
    if (t == 0) {
        float l0 = bc[0], l1 = bc[1];
#pragma unroll
        for (int dd = 0; dd < 32; ++dd) {
            l0 += h3[dd] * Wc[2 * dd];
            l1 += h3[dd] * Wc[2 * dd + 1];
        }
        float m  = fmaxf(l0, l1);
        float e0 = expf(l0 - m), e1 = expf(l1 - m);
        float inv = 1.0f / (e0 + e1);
        out[2 * s]     = e0 * inv;
        out[2 * s + 1] = e1 * inv;
    }
}

// ---------------- masked row max/argmax -> new labels ------------------------
__global__ void newlab_kernel(const float* __restrict__ aff,
                              const int* __restrict__ lab,
                              float* __restrict__ out) {
    int i    = blockIdx.x;
    int lane = threadIdx.x;
    float best = -INFINITY;
    int   bidx = 0x7FFFFFFF;
    for (int j = lane; j < NSEG; j += 64) {
        if (lab[j] != 0) {
            float v = aff[(size_t)i * NSEG + j];
            if (v > best) { best = v; bidx = j; }
        }
    }
    for (int off = 32; off; off >>= 1) {
        float ov = __shfl_down(best, off);
        int   oi = __shfl_down(bidx, off);
        if (ov > best || (ov == best && oi < bidx)) { best = ov; bidx = oi; }
    }
    if (lane == 0) {
        int li = lab[i];
        int nl = li;
        if (li == 0 && best >= 0.7f && bidx != 0x7FFFFFFF) nl = lab[bidx];
        out[880 + i] = (float)nl;
    }
}

extern "C" void kernel_launch(void* const* d_in, const int* in_sizes, int n_in,
                              void* d_out, int out_size, void* d_ws, size_t ws_size,
                              hipStream_t stream) {
    const float* fm = (const float*)d_in[0];
    const int*   sp = (const int*)d_in[1];
    const int*   y  = (const int*)d_in[2];
    const float* W1 = (const float*)d_in[3];
    const float* b1 = (const float*)d_in[4];
    const float* W2 = (const float*)d_in[5];
    const float* b2 = (const float*)d_in[6];
    const float* W3 = (const float*)d_in[7];
    const float* b3 = (const float*)d_in[8];
    const float* Wc = (const float*)d_in[9];
    const float* bc = (const float*)d_in[10];
    float* out = (float*)d_out;
    float* ws  = (float*)d_ws;

    float* hist = ws + OFF_HIST;
    float* feat = ws + OFF_FEAT;
    float* h1   = ws + OFF_H1;
    float* h2   = ws + OFF_H2;
    float* aff  = ws + OFF_AFF;
    float* invn = ws + OFF_INVN;
    int*   lab  = (int*)(ws + OFF_LAB);

    hipMemsetAsync(hist, 0, NSEG * 3 * sizeof(float), stream);
    hist_kernel<<<64, 256, 0, stream>>>(sp, y, hist);
    segsum_kernel<<<CF, 256, 0, stream>>>(fm, sp, hist, feat);
    lab_kernel<<<2, 256, 0, stream>>>(hist, lab);

    gemm_nn<1><<<dim3(16, 7), 256, 0, stream>>>(feat, W1, b1, h1, NSEG, NH, CF);
    gemm_nn<1><<<dim3(16, 7), 256, 0, stream>>>(h1, W2, b2, h2, NSEG, NH, NH);
    head_kernel<<<NSEG, 256, 0, stream>>>(h2, W3, b3, Wc, bc, out);

    norm_kernel<<<NSEG, 256, 0, stream>>>(feat, invn);
    gemm_nt_aff<<<dim3(7, 7), 256, 0, stream>>>(feat, invn, aff);
    newlab_kernel<<<NSEG, 64, 0, stream>>>(aff, lab, out);
}